// Round 1
// baseline (6038.685 us; speedup 1.0000x reference)
//
#include <hip/hip_runtime.h>
#include <cmath>

#define NWG 256
#define NT  256

// dims: B=16, T=64, L=64, D=512, A=256, 4D=2048
// ws float offsets
#define WS_H     0         // 16*512
#define WS_CV    8192      // 16*512
#define WS_HC    16384     // 16*512
#define WS_HW1   24576     // 16*256
#define WS_HW1H  28672     // 16*256
#define WS_CT    32768     // 16*64*256
#define WS_CACHE 294912    // 16*64*256
#define WS_HIST  557056    // 16*64*512
#define WS_CTR   1081344   // u32 barrier counter region (needs ~4.33 MB total ws)

// out float offsets (hs | cs | ctxs)
#define OUT_HS  0
#define OUT_CS  524288
#define OUT_CTX 1048576

// lds float offsets
#define LDS_WT   0        // 8 cols x 2568 (2560 rows + pad)
#define LDS_ZS   20544    // z-stage [512][20]  (k-major, padded rows)
#define LDS_PC   30784    // 3 proj cols x 512
#define LDS_SCR  32320    // reduce scratch 16*16*8
#define LDS_GLD  34368    // g lds 16*8
#define LDS_FLOATS 34496  // *4 = 137,984 B < 160 KB

struct CAParams {
  const float* X; const float* ctx; const int* parent; const int* cmask; const float* mask;
  const float* Wx; const float* bx; const float* U; const float* C; const float* P; const float* H;
  const float* acW1; const float* ab1; const float* ahW1; const float* aW2; const float* ab2;
  const float* hhW; const float* hhb; const float* hthW1; const float* hW2; const float* hb2;
  float* out; float* ws;
};

__device__ __forceinline__ float tanh_f(float x) {
  x = fminf(15.f, fmaxf(-15.f, x));
  float e = __expf(2.f * x);
  return (e - 1.f) / (e + 1.f);
}
__device__ __forceinline__ float sigm_f(float x) { return 1.f / (1.f + __expf(-x)); }
__device__ __forceinline__ float wsum(float v) {
  #pragma unroll
  for (int m = 32; m; m >>= 1) v += __shfl_xor(v, m, 64);
  return v;
}
__device__ __forceinline__ float wmax(float v) {
  #pragma unroll
  for (int m = 32; m; m >>= 1) v = fmaxf(v, __shfl_xor(v, m, 64));
  return v;
}

__global__ void __launch_bounds__(NT, 1) condatt_kernel(CAParams p) {
  extern __shared__ float lds[];
  float* wt  = lds + LDS_WT;
  float* zs  = lds + LDS_ZS;
  float* pc  = lds + LDS_PC;
  float* scr = lds + LDS_SCR;
  float* gld = lds + LDS_GLD;

  const int tid = threadIdx.x;
  const int wg  = blockIdx.x;
  unsigned* ctr = (unsigned*)(p.ws + WS_CTR);
  unsigned nbar = 0;

  const int kh = tid >> 4, sub = tid & 15, bg = sub >> 2, cp = sub & 3;
  float acc[4][2] = {{0.f,0.f},{0.f,0.f},{0.f,0.f},{0.f,0.f}};
  float hprev = 0.f, cprev = 0.f;  // used by threads 0..31 (per-(b,d) state)

  auto gsync = [&]() {
    __syncthreads();
    ++nbar;
    if (tid == 0) {
      __hip_atomic_fetch_add(ctr, 1u, __ATOMIC_ACQ_REL, __HIP_MEMORY_SCOPE_AGENT);
      unsigned tgt = nbar * (unsigned)NWG;
      while (__hip_atomic_load(ctr, __ATOMIC_RELAXED, __HIP_MEMORY_SCOPE_AGENT) < tgt)
        __builtin_amdgcn_s_sleep(2);
      (void)__hip_atomic_load(ctr, __ATOMIC_ACQUIRE, __HIP_MEMORY_SCOPE_AGENT);
    }
    __syncthreads();
  };

  // ---------------- prologue ----------------
  {
    // persistent gate-GEMM weight columns: rows 0..511=Wx, 512..1023=U, 1024..1535=P, 1536..2047=C, 2048..2559=H
    const float* mats[5] = {p.Wx, p.U, p.P, p.C, p.H};
    for (int i = tid; i < 8 * 2560; i += NT) {
      int c = i / 2560, r = i - c * 2560;
      int m = r >> 9, rr = r & 511;
      int n = 2 * wg + (c >> 2) + 512 * (c & 3);
      wt[c * 2568 + r] = mats[m][rr * 2048 + n];
    }
    // persistent projection columns (col index = wg) of att_h_W1, hatt_h_W1, hatt_hist_W
    const float* pm[3] = {p.ahW1, p.hthW1, p.hhW};
    for (int i = tid; i < 3 * 512; i += NT) {
      int m = i >> 9, d = i & 511;
      pc[i] = pm[m][d * 256 + wg];
    }
    // zero cache (histW) and h
    for (int i = wg * NT + tid; i < 262144 + 8192; i += NWG * NT) {
      if (i < 262144) p.ws[WS_CACHE + i] = 0.f;
      else            p.ws[WS_H + (i - 262144)] = 0.f;
    }
    // ctx_trans = context @ att_ctx_W1 + att_b1 : 4 (b,l)-rows per wg, thread = a
    for (int j = 0; j < 4; ++j) {
      int rid = wg * 4 + j;  // rid = b*64 + l
      __syncthreads();
      for (int i = tid; i < 512; i += NT) scr[i] = p.ctx[rid * 512 + i];
      __syncthreads();
      float a0 = 0.f, a1 = 0.f, a2 = 0.f, a3 = 0.f;
      for (int c = 0; c < 512; c += 4) {
        a0 += scr[c+0] * p.acW1[(c+0) * 256 + tid];
        a1 += scr[c+1] * p.acW1[(c+1) * 256 + tid];
        a2 += scr[c+2] * p.acW1[(c+2) * 256 + tid];
        a3 += scr[c+3] * p.acW1[(c+3) * 256 + tid];
      }
      p.ws[WS_CT + rid * 256 + tid] = p.ab1[tid] + ((a0 + a1) + (a2 + a3));
    }
  }
  gsync();

  auto stageX = [&](int t) {
    for (int i = tid; i < 8192; i += NT) { int b = i >> 9, k = i & 511; zs[k*20 + b] = p.X[(b*64 + t)*512 + k]; }
  };
  auto stageWS = [&](int off) {
    for (int i = tid; i < 8192; i += NT) { int b = i >> 9, k = i & 511; zs[k*20 + b] = p.ws[off + b*512 + k]; }
  };
  auto stagePar = [&](int t) {
    for (int i = tid; i < 8192; i += NT) {
      int b = i >> 9, k = i & 511;
      int par = p.parent[b*64 + t];
      zs[k*20 + b] = (t > 0 && par < t) ? p.ws[WS_HIST + (b*64 + par)*512 + k] : 0.f;
    }
  };
  auto gemm = [&](int comp) {
    const float* w0p = wt + (cp*2  )*2568 + comp*512;
    const float* w1p = wt + (cp*2+1)*2568 + comp*512;
    #pragma unroll 4
    for (int j = 0; j < 32; ++j) {
      int k = kh + (j << 4);
      float4 zv = *(const float4*)(zs + k*20 + bg*4);
      float w0 = w0p[k], w1 = w1p[k];
      acc[0][0] += zv.x * w0; acc[0][1] += zv.x * w1;
      acc[1][0] += zv.y * w0; acc[1][1] += zv.y * w1;
      acc[2][0] += zv.z * w0; acc[2][1] += zv.z * w1;
      acc[3][0] += zv.w * w0; acc[3][1] += zv.w * w1;
    }
  };

  // attention scratch aliases zs
  float* aw   = zs;        // 256
  float* av2  = zs + 256;  // 256
  float* abv  = zs + 512;  // 256
  float* araw = zs + 768;  // 64
  float* asmx = zs + 832;  // 64

  for (int t = 0; t < 64; ++t) {
    // ---- P0: projections (h@attW1, h@hattW1, cache row t-1) + partial gate GEMM (x,h,par_h) ----
    __syncthreads(); stageX(t);
    __syncthreads(); gemm(0);
    __syncthreads(); stageWS(WS_H);
    __syncthreads();
    {
      int w = tid >> 6, lane = tid & 63;
      for (int j = w * 12; j < w * 12 + 12; ++j) {
        int m = j >> 4, b = j & 15;
        float s = 0.f;
        #pragma unroll
        for (int e = 0; e < 8; ++e) { int k = lane + (e << 6); s += zs[k*20 + b] * pc[m*512 + k]; }
        s = wsum(s);
        if (lane == 0) {
          if (m == 0)      p.ws[WS_HW1  + b*256 + wg] = s;
          else if (m == 1) p.ws[WS_HW1H + b*256 + wg] = s;
          else if (t > 0)  p.ws[WS_CACHE + (b*64 + (t-1))*256 + wg] = s;
        }
      }
    }
    gemm(1);
    __syncthreads(); stagePar(t);
    __syncthreads(); gemm(2);
    gsync();

    // ---- P1: attention (wg 0..15 ctx-att for b=wg; wg 16..31 hist-att for b=wg-16) ----
    __syncthreads();
    if (wg < 16) {
      for (int i = tid; i < 256; i += NT) { aw[i] = p.ws[WS_HW1 + wg*256 + i]; av2[i] = p.aW2[i]; }
    } else if (wg < 32) {
      int b = wg - 16;
      for (int i = tid; i < 256; i += NT) { aw[i] = p.ws[WS_HW1H + b*256 + i]; av2[i] = p.hW2[i]; abv[i] = p.hhb[i]; }
    }
    __syncthreads();
    if (wg < 16) {
      int b = wg, w = tid >> 6, lane = tid & 63;
      float b2 = *p.ab2;
      for (int l = w; l < 64; l += 4) {
        float s = 0.f;
        #pragma unroll
        for (int q = 0; q < 4; ++q) { int a = lane + (q << 6); s += av2[a] * tanh_f(p.ws[WS_CT + (b*64 + l)*256 + a] + aw[a]); }
        s = wsum(s) + b2;
        if (lane == 0) araw[l] = (p.cmask[b*64 + l] > 0) ? -INFINITY : s;
      }
    } else if (wg < 32) {
      int b = wg - 16, w = tid >> 6, lane = tid & 63;
      float b2 = *p.hb2;
      for (int l = w; l < 64; l += 4) {
        float s = 0.f;
        #pragma unroll
        for (int q = 0; q < 4; ++q) { int a = lane + (q << 6); s += av2[a] * tanh_f(p.ws[WS_CACHE + (b*64 + l)*256 + a] + abv[a] + aw[a]); }
        s = wsum(s) + b2;
        if (lane == 0) araw[l] = s;
      }
    }
    __syncthreads();
    if (wg < 16 && tid < 64) {
      float r = araw[tid];
      float mx = wmax(r);
      float e = __expf(r - mx);
      float sm = wsum(e);
      asmx[tid] = e / sm;
    } else if (wg >= 16 && wg < 32 && tid < 64) {
      float r = araw[tid];
      float mx = wmax(r);                    // max over ALL t' (matches reference)
      float e = (tid < t) ? __expf(r - mx) : 0.f;
      float sm = wsum(e);
      asmx[tid] = e / (sm + 1e-7f);
    }
    __syncthreads();
    if (wg < 16) {
      int b = wg;
      float a0 = 0.f, a1 = 0.f;
      for (int l = 0; l < 64; ++l) {
        float ca = asmx[l];
        a0 += ca * p.ctx[(b*64 + l)*512 + tid];
        a1 += ca * p.ctx[(b*64 + l)*512 + 256 + tid];
      }
      p.ws[WS_CV + b*512 + tid] = a0;
      p.ws[WS_CV + b*512 + 256 + tid] = a1;
      p.out[OUT_CTX + (b*64 + t)*512 + tid] = a0;
      p.out[OUT_CTX + (b*64 + t)*512 + 256 + tid] = a1;
    } else if (wg < 32) {
      int b = wg - 16;
      float a0 = 0.f, a1 = 0.f;
      for (int l = 0; l < t; ++l) {
        float hv = asmx[l];
        a0 += hv * p.ws[WS_HIST + (b*64 + l)*512 + tid];
        a1 += hv * p.ws[WS_HIST + (b*64 + l)*512 + 256 + tid];
      }
      p.ws[WS_HC + b*512 + tid] = a0;
      p.ws[WS_HC + b*512 + 256 + tid] = a1;
    }
    gsync();

    // ---- P2: + ctx_vec@C + h_ctx@H, gates, state update ----
    __syncthreads(); stageWS(WS_CV);
    __syncthreads(); gemm(3);
    __syncthreads(); stageWS(WS_HC);
    __syncthreads(); gemm(4);
    __syncthreads();
    {
      float* s8 = scr + (kh*16 + sub)*8;
      #pragma unroll
      for (int i = 0; i < 4; ++i) { s8[i*2] = acc[i][0]; s8[i*2+1] = acc[i][1]; acc[i][0] = 0.f; acc[i][1] = 0.f; }
    }
    __syncthreads();
    if (tid < 128) {
      int b = tid >> 3, c = tid & 7;
      int n = 2*wg + (c >> 2) + 512*(c & 3);
      float g = p.bx[n];
      int sidx = (b >> 2)*4 + (c >> 1);
      int aidx = (b & 3)*2 + (c & 1);
      #pragma unroll
      for (int k2 = 0; k2 < 16; ++k2) g += scr[(k2*16 + sidx)*8 + aidx];
      gld[b*8 + c] = g;
    }
    __syncthreads();
    if (tid < 32) {
      int b = tid >> 1, dj = tid & 1;
      int d = 2*wg + dj;
      float gi = gld[b*8 + dj*4 + 0];
      float gf = gld[b*8 + dj*4 + 1];
      float gg = gld[b*8 + dj*4 + 2];
      float go = gld[b*8 + dj*4 + 3];
      float i_ = sigm_f(gi), f_ = sigm_f(gf), o_ = sigm_f(go);
      float cn = f_*cprev + i_*tanh_f(gg);
      float hn = o_*tanh_f(cn);
      float m_ = p.mask[b*64 + t];
      hn = (1.f - m_)*hprev + m_*hn;
      cn = (1.f - m_)*cprev + m_*cn;
      hprev = hn; cprev = cn;
      p.ws[WS_H + b*512 + d] = hn;
      p.ws[WS_HIST + (b*64 + t)*512 + d] = hn;
      p.out[OUT_HS + (b*64 + t)*512 + d] = hn;
      p.out[OUT_CS + (b*64 + t)*512 + d] = cn;
    }
    gsync();
  }
}

extern "C" void kernel_launch(void* const* d_in, const int* in_sizes, int n_in,
                              void* d_out, int out_size, void* d_ws, size_t ws_size,
                              hipStream_t stream) {
  CAParams p;
  p.X      = (const float*)d_in[0];
  p.ctx    = (const float*)d_in[1];
  p.parent = (const int*)  d_in[2];
  p.cmask  = (const int*)  d_in[3];
  p.mask   = (const float*)d_in[4];
  p.Wx = (const float*)d_in[5];  p.bx = (const float*)d_in[6];
  p.U  = (const float*)d_in[7];  p.C  = (const float*)d_in[8];
  p.P  = (const float*)d_in[9];  p.H  = (const float*)d_in[10];
  p.acW1 = (const float*)d_in[11]; p.ab1 = (const float*)d_in[12];
  p.ahW1 = (const float*)d_in[13]; p.aW2 = (const float*)d_in[14]; p.ab2 = (const float*)d_in[15];
  p.hhW  = (const float*)d_in[16]; p.hhb = (const float*)d_in[17];
  p.hthW1= (const float*)d_in[18]; p.hW2 = (const float*)d_in[19]; p.hb2 = (const float*)d_in[20];
  p.out = (float*)d_out;
  p.ws  = (float*)d_ws;

  // reset barrier counters (ws is poisoned once before timing; replays leave it nonzero)
  hipMemsetAsync((char*)d_ws + (size_t)WS_CTR * sizeof(float), 0, 256, stream);

  static_assert(LDS_FLOATS * 4 <= 160 * 1024, "LDS budget");
  hipFuncSetAttribute((const void*)condatt_kernel,
                      hipFuncAttributeMaxDynamicSharedMemorySize, LDS_FLOATS * 4);
  hipLaunchKernelGGL(condatt_kernel, dim3(NWG), dim3(NT), LDS_FLOATS * 4, stream, p);
}

// Round 2
// 5186.646 us; speedup vs baseline: 1.1643x; 1.1643x over previous
//
#include <hip/hip_runtime.h>
#include <cmath>

#define NWG 256
#define NT  256

// dims: B=16, T=64, L=64, D=512, A=256, 4D=2048
// ws float offsets
#define WS_H     0         // 16*512
#define WS_CV    8192      // 16*512
#define WS_HC    16384     // 16*512
#define WS_HW1   24576     // 16*256
#define WS_HW1H  28672     // 16*256
#define WS_CT    32768     // 16*64*256
#define WS_CACHE 294912    // 16*64*256
#define WS_HIST  557056    // 16*64*512
#define WS_CTR   1081344   // u32 flags[256] (1 KB)

// out float offsets (hs | cs | ctxs)
#define OUT_HS  0
#define OUT_CS  524288
#define OUT_CTX 1048576

// lds float offsets
#define LDS_WT   0        // 8 cols x 2568 (2560 rows + pad)
#define LDS_ZS   20544    // z-stage [512][20]  (k-major, padded rows)
#define LDS_PC   30784    // 3 proj cols x 512
#define LDS_SCR  32320    // reduce scratch 16*16*8
#define LDS_GLD  34368    // g lds 16*8
#define LDS_FLOATS 34496  // *4 = 137,984 B < 160 KB

struct CAParams {
  const float* X; const float* ctx; const int* parent; const int* cmask; const float* mask;
  const float* Wx; const float* bx; const float* U; const float* C; const float* P; const float* H;
  const float* acW1; const float* ab1; const float* ahW1; const float* aW2; const float* ab2;
  const float* hhW; const float* hhb; const float* hthW1; const float* hW2; const float* hb2;
  float* out; float* ws;
};

__device__ __forceinline__ float tanh_f(float x) {
  x = fminf(15.f, fmaxf(-15.f, x));
  float e = __expf(2.f * x);
  return (e - 1.f) / (e + 1.f);
}
__device__ __forceinline__ float sigm_f(float x) { return 1.f / (1.f + __expf(-x)); }
__device__ __forceinline__ float wsum(float v) {
  #pragma unroll
  for (int m = 32; m; m >>= 1) v += __shfl_xor(v, m, 64);
  return v;
}
__device__ __forceinline__ float wmax(float v) {
  #pragma unroll
  for (int m = 32; m; m >>= 1) v = fmaxf(v, __shfl_xor(v, m, 64));
  return v;
}
// MALL-coherent (L1/L2-bypassing) accesses for cross-WG mutable data.
// Relaxed => no fences, no cache invalidation, fully pipelined.
__device__ __forceinline__ float wld(const float* a) {
  return __hip_atomic_load(a, __ATOMIC_RELAXED, __HIP_MEMORY_SCOPE_SYSTEM);
}
__device__ __forceinline__ void wst(float* a, float v) {
  __hip_atomic_store(a, v, __ATOMIC_RELAXED, __HIP_MEMORY_SCOPE_SYSTEM);
}

__global__ void __launch_bounds__(NT, 1) condatt_kernel(CAParams p) {
  extern __shared__ float lds[];
  float* wt  = lds + LDS_WT;
  float* zs  = lds + LDS_ZS;
  float* pc  = lds + LDS_PC;
  float* scr = lds + LDS_SCR;
  float* gld = lds + LDS_GLD;

  const int tid = threadIdx.x;
  const int wg  = blockIdx.x;
  float* wsp = p.ws;
  unsigned* flags = (unsigned*)(wsp + WS_CTR);
  unsigned nbar = 0;

  const int kh = tid >> 4, sub = tid & 15, bg = sub >> 2, cp = sub & 3;
  float acc[4][2] = {{0.f,0.f},{0.f,0.f},{0.f,0.f},{0.f,0.f}};
  float hprev = 0.f, cprev = 0.f;  // threads 0..31: per-(b,d) state

  // Flag-array grid barrier: no RMW contention, no acquire-invalidate.
  // Producer side: each thread drains its own bypassing stores (vmcnt(0)),
  // WG-barrier, then tid0 publishes flags[wg]=seq at the MALL. Consumers
  // poll one flag each with relaxed bypassing loads; MALL ordering makes
  // data (stored via wst before the flag) visible.
  auto gsync = [&]() {
    asm volatile("s_waitcnt vmcnt(0)" ::: "memory");
    __syncthreads();
    ++nbar;
    if (tid == 0)
      __hip_atomic_store(&flags[wg], nbar, __ATOMIC_RELAXED, __HIP_MEMORY_SCOPE_SYSTEM);
    while (__hip_atomic_load(&flags[tid], __ATOMIC_RELAXED, __HIP_MEMORY_SCOPE_SYSTEM) < nbar)
      __builtin_amdgcn_s_sleep(1);
    __syncthreads();
  };

  // ---------------- prologue ----------------
  {
    // persistent gate-GEMM weight columns: rows 0..511=Wx, 512..1023=U, 1024..1535=P, 1536..2047=C, 2048..2559=H
    const float* mats[5] = {p.Wx, p.U, p.P, p.C, p.H};
    for (int i = tid; i < 8 * 2560; i += NT) {
      int c = i / 2560, r = i - c * 2560;
      int m = r >> 9, rr = r & 511;
      int n = 2 * wg + (c >> 2) + 512 * (c & 3);
      wt[c * 2568 + r] = mats[m][rr * 2048 + n];
    }
    // persistent projection columns (col index = wg) of att_h_W1, hatt_h_W1, hatt_hist_W
    const float* pm[3] = {p.ahW1, p.hthW1, p.hhW};
    for (int i = tid; i < 3 * 512; i += NT) {
      int m = i >> 9, d = i & 511;
      pc[i] = pm[m][d * 256 + wg];
    }
    // zero cache (histW) and h
    for (int i = wg * NT + tid; i < 262144 + 8192; i += NWG * NT) {
      if (i < 262144) wst(wsp + WS_CACHE + i, 0.f);
      else            wst(wsp + WS_H + (i - 262144), 0.f);
    }
    // ctx_trans = context @ att_ctx_W1 + att_b1 : 4 (b,l)-rows per wg, thread = a
    for (int j = 0; j < 4; ++j) {
      int rid = wg * 4 + j;  // rid = b*64 + l
      __syncthreads();
      for (int i = tid; i < 512; i += NT) scr[i] = p.ctx[rid * 512 + i];
      __syncthreads();
      float a0 = 0.f, a1 = 0.f, a2 = 0.f, a3 = 0.f;
      for (int c = 0; c < 512; c += 4) {
        a0 += scr[c+0] * p.acW1[(c+0) * 256 + tid];
        a1 += scr[c+1] * p.acW1[(c+1) * 256 + tid];
        a2 += scr[c+2] * p.acW1[(c+2) * 256 + tid];
        a3 += scr[c+3] * p.acW1[(c+3) * 256 + tid];
      }
      wst(wsp + WS_CT + rid * 256 + tid, p.ab1[tid] + ((a0 + a1) + (a2 + a3)));
    }
  }
  gsync();

  auto stageX = [&](int t) {
    #pragma unroll
    for (int i = tid; i < 8192; i += NT) { int b = i >> 9, k = i & 511; zs[k*20 + b] = p.X[(b*64 + t)*512 + k]; }
  };
  auto stageWS = [&](int off) {
    #pragma unroll
    for (int i = tid; i < 8192; i += NT) { int b = i >> 9, k = i & 511; zs[k*20 + b] = wld(wsp + off + b*512 + k); }
  };
  auto stagePar = [&](int t) {
    #pragma unroll
    for (int i = tid; i < 8192; i += NT) {
      int b = i >> 9, k = i & 511;
      int par = p.parent[b*64 + t];
      zs[k*20 + b] = (t > 0 && par < t) ? wld(wsp + WS_HIST + (b*64 + par)*512 + k) : 0.f;
    }
  };
  auto gemm = [&](int comp) {
    const float* w0p = wt + (cp*2  )*2568 + comp*512;
    const float* w1p = wt + (cp*2+1)*2568 + comp*512;
    #pragma unroll 4
    for (int j = 0; j < 32; ++j) {
      int k = kh + (j << 4);
      float4 zv = *(const float4*)(zs + k*20 + bg*4);
      float w0 = w0p[k], w1 = w1p[k];
      acc[0][0] += zv.x * w0; acc[0][1] += zv.x * w1;
      acc[1][0] += zv.y * w0; acc[1][1] += zv.y * w1;
      acc[2][0] += zv.z * w0; acc[2][1] += zv.z * w1;
      acc[3][0] += zv.w * w0; acc[3][1] += zv.w * w1;
    }
  };

  // attention scratch aliases zs
  float* aw   = zs;        // 256
  float* av2  = zs + 256;  // 256
  float* abv  = zs + 512;  // 256
  float* araw = zs + 768;  // 64
  float* asmx = zs + 832;  // 64

  for (int t = 0; t < 64; ++t) {
    // ---- P0: projections (h@attW1, h@hattW1, cache row t-1) + partial gate GEMM (x,h,par_h) ----
    __syncthreads(); stageX(t);
    __syncthreads(); gemm(0);
    __syncthreads(); stageWS(WS_H);
    __syncthreads();
    {
      int w = tid >> 6, lane = tid & 63;
      for (int j = w * 12; j < w * 12 + 12; ++j) {
        int m = j >> 4, b = j & 15;
        float s = 0.f;
        #pragma unroll
        for (int e = 0; e < 8; ++e) { int k = lane + (e << 6); s += zs[k*20 + b] * pc[m*512 + k]; }
        s = wsum(s);
        if (lane == 0) {
          if (m == 0)      wst(wsp + WS_HW1  + b*256 + wg, s);
          else if (m == 1) wst(wsp + WS_HW1H + b*256 + wg, s);
          else if (t > 0)  wst(wsp + WS_CACHE + (b*64 + (t-1))*256 + wg, s);
        }
      }
    }
    gemm(1);
    __syncthreads(); stagePar(t);
    __syncthreads(); gemm(2);
    gsync();

    // ---- P1: attention (wg 0..15 ctx-att for b=wg; wg 16..31 hist-att for b=wg-16) ----
    __syncthreads();
    if (wg < 16) {
      for (int i = tid; i < 256; i += NT) { aw[i] = wld(wsp + WS_HW1 + wg*256 + i); av2[i] = p.aW2[i]; }
    } else if (wg < 32) {
      int b = wg - 16;
      for (int i = tid; i < 256; i += NT) { aw[i] = wld(wsp + WS_HW1H + b*256 + i); av2[i] = p.hW2[i]; abv[i] = p.hhb[i]; }
    }
    __syncthreads();
    if (wg < 16) {
      int b = wg, w = tid >> 6, lane = tid & 63;
      float b2 = *p.ab2;
      for (int l = w; l < 64; l += 4) {
        float s = 0.f;
        #pragma unroll
        for (int q = 0; q < 4; ++q) { int a = lane + (q << 6); s += av2[a] * tanh_f(p.ws[WS_CT + (b*64 + l)*256 + a] + aw[a]); }
        s = wsum(s) + b2;
        if (lane == 0) araw[l] = (p.cmask[b*64 + l] > 0) ? -INFINITY : s;
      }
    } else if (wg < 32) {
      int b = wg - 16, w = tid >> 6, lane = tid & 63;
      float b2 = *p.hb2;
      for (int l = w; l < 64; l += 4) {
        float s = 0.f;
        #pragma unroll
        for (int q = 0; q < 4; ++q) { int a = lane + (q << 6); s += av2[a] * tanh_f(wld(wsp + WS_CACHE + (b*64 + l)*256 + a) + abv[a] + aw[a]); }
        s = wsum(s) + b2;
        if (lane == 0) araw[l] = s;
      }
    }
    __syncthreads();
    if (wg < 16 && tid < 64) {
      float r = araw[tid];
      float mx = wmax(r);
      float e = __expf(r - mx);
      float sm = wsum(e);
      asmx[tid] = e / sm;
    } else if (wg >= 16 && wg < 32 && tid < 64) {
      float r = araw[tid];
      float mx = wmax(r);                    // max over ALL t' (matches reference)
      float e = (tid < t) ? __expf(r - mx) : 0.f;
      float sm = wsum(e);
      asmx[tid] = e / (sm + 1e-7f);
    }
    __syncthreads();
    if (wg < 16) {
      int b = wg;
      float a0 = 0.f, a1 = 0.f;
      #pragma unroll 8
      for (int l = 0; l < 64; ++l) {
        float ca = asmx[l];
        a0 += ca * p.ctx[(b*64 + l)*512 + tid];
        a1 += ca * p.ctx[(b*64 + l)*512 + 256 + tid];
      }
      wst(wsp + WS_CV + b*512 + tid, a0);
      wst(wsp + WS_CV + b*512 + 256 + tid, a1);
      p.out[OUT_CTX + (b*64 + t)*512 + tid] = a0;
      p.out[OUT_CTX + (b*64 + t)*512 + 256 + tid] = a1;
    } else if (wg < 32) {
      int b = wg - 16;
      float a0 = 0.f, a1 = 0.f;
      // full 64 iterations (compile-time bound, deep MLP); asmx[l]=0 for l>=t
      #pragma unroll 8
      for (int l = 0; l < 64; ++l) {
        float hv = asmx[l];
        a0 += hv * wld(wsp + WS_HIST + (b*64 + l)*512 + tid);
        a1 += hv * wld(wsp + WS_HIST + (b*64 + l)*512 + 256 + tid);
      }
      wst(wsp + WS_HC + b*512 + tid, a0);
      wst(wsp + WS_HC + b*512 + 256 + tid, a1);
    }
    gsync();

    // ---- P2: + ctx_vec@C + h_ctx@H, gates, state update ----
    __syncthreads(); stageWS(WS_CV);
    __syncthreads(); gemm(3);
    __syncthreads(); stageWS(WS_HC);
    __syncthreads(); gemm(4);
    __syncthreads();
    {
      float* s8 = scr + (kh*16 + sub)*8;
      #pragma unroll
      for (int i = 0; i < 4; ++i) { s8[i*2] = acc[i][0]; s8[i*2+1] = acc[i][1]; acc[i][0] = 0.f; acc[i][1] = 0.f; }
    }
    __syncthreads();
    if (tid < 128) {
      int b = tid >> 3, c = tid & 7;
      int n = 2*wg + (c >> 2) + 512*(c & 3);
      float g = p.bx[n];
      int sidx = (b >> 2)*4 + (c >> 1);
      int aidx = (b & 3)*2 + (c & 1);
      #pragma unroll
      for (int k2 = 0; k2 < 16; ++k2) g += scr[(k2*16 + sidx)*8 + aidx];
      gld[b*8 + c] = g;
    }
    __syncthreads();
    if (tid < 32) {
      int b = tid >> 1, dj = tid & 1;
      int d = 2*wg + dj;
      float gi = gld[b*8 + dj*4 + 0];
      float gf = gld[b*8 + dj*4 + 1];
      float gg = gld[b*8 + dj*4 + 2];
      float go = gld[b*8 + dj*4 + 3];
      float i_ = sigm_f(gi), f_ = sigm_f(gf), o_ = sigm_f(go);
      float cn = f_*cprev + i_*tanh_f(gg);
      float hn = o_*tanh_f(cn);
      float m_ = p.mask[b*64 + t];
      hn = (1.f - m_)*hprev + m_*hn;
      cn = (1.f - m_)*cprev + m_*cn;
      hprev = hn; cprev = cn;
      wst(wsp + WS_H + b*512 + d, hn);
      wst(wsp + WS_HIST + (b*64 + t)*512 + d, hn);
      p.out[OUT_HS + (b*64 + t)*512 + d] = hn;
      p.out[OUT_CS + (b*64 + t)*512 + d] = cn;
    }
    gsync();
  }
}

extern "C" void kernel_launch(void* const* d_in, const int* in_sizes, int n_in,
                              void* d_out, int out_size, void* d_ws, size_t ws_size,
                              hipStream_t stream) {
  CAParams p;
  p.X      = (const float*)d_in[0];
  p.ctx    = (const float*)d_in[1];
  p.parent = (const int*)  d_in[2];
  p.cmask  = (const int*)  d_in[3];
  p.mask   = (const float*)d_in[4];
  p.Wx = (const float*)d_in[5];  p.bx = (const float*)d_in[6];
  p.U  = (const float*)d_in[7];  p.C  = (const float*)d_in[8];
  p.P  = (const float*)d_in[9];  p.H  = (const float*)d_in[10];
  p.acW1 = (const float*)d_in[11]; p.ab1 = (const float*)d_in[12];
  p.ahW1 = (const float*)d_in[13]; p.aW2 = (const float*)d_in[14]; p.ab2 = (const float*)d_in[15];
  p.hhW  = (const float*)d_in[16]; p.hhb = (const float*)d_in[17];
  p.hthW1= (const float*)d_in[18]; p.hW2 = (const float*)d_in[19]; p.hb2 = (const float*)d_in[20];
  p.out = (float*)d_out;
  p.ws  = (float*)d_ws;

  // reset barrier flags (seq restarts at 1 each launch)
  hipMemsetAsync((char*)d_ws + (size_t)WS_CTR * sizeof(float), 0, 1024, stream);

  static_assert(LDS_FLOATS * 4 <= 160 * 1024, "LDS budget");
  hipFuncSetAttribute((const void*)condatt_kernel,
                      hipFuncAttributeMaxDynamicSharedMemorySize, LDS_FLOATS * 4);
  hipLaunchKernelGGL(condatt_kernel, dim3(NWG), dim3(NT), LDS_FLOATS * 4, stream, p);
}

// Round 4
// 3663.137 us; speedup vs baseline: 1.6485x; 1.4159x over previous
//
#include <hip/hip_runtime.h>
#include <cmath>

#define NWG 256
#define NT  256

// dims: B=16, T=64, L=64, D=512, A=256, 4D=2048
// ws float offsets
#define WS_HW1   0         // 16*256   (h@att_h_W1, rewritten per step; bypass-only)
#define WS_HW1H  4096      // 16*256   (h@hatt_h_W1, bypass-only)
#define WS_HC    8192      // 16*512   (h_ctx, bypass-only)
#define WS_CT    16384     // 16*64*256 ctx_trans (write-once prologue, cached reads)
#define WS_CACHE 278528    // 16*64*256 hist@hatt_hist_W rows (write-once per row, cached reads)
#define WS_HIST  540672    // 16*64*512 h history rows (write-once per row, cached reads)
#define WS_CTR   1064960   // u32 barrier counter (reset each launch)

// out float offsets (hs | cs | ctxs)
#define OUT_HS  0
#define OUT_CS  524288
#define OUT_CTX 1048576

// lds float offsets
#define LDS_WT   0        // 4 cp * 5136 (2560 K * 2 cols interleaved + pad)
#define LDS_ZS   20544    // z-stage [16 b][516]
#define LDS_PC   28800    // 3 proj cols x 512
#define LDS_SCR  30336    // reduce scratch 16*16*8
#define LDS_GLD  32384    // g lds 16*8
#define LDS_ATT  32512    // aw 256 | av2 256 | abv 256 | araw 64 | asmx 64 | arawZ 64
#define LDS_FLOATS 33472  // *4 = 133,888 B < 160 KB

typedef float vf4 __attribute__((ext_vector_type(4)));
typedef float vf2 __attribute__((ext_vector_type(2)));

struct CAParams {
  const float* X; const float* ctx; const int* parent; const int* cmask; const float* mask;
  const float* Wx; const float* bx; const float* U; const float* C; const float* P; const float* H;
  const float* acW1; const float* ab1; const float* ahW1; const float* aW2; const float* ab2;
  const float* hhW; const float* hhb; const float* hthW1; const float* hW2; const float* hb2;
  float* out; float* ws;
};

__device__ __forceinline__ float tanh_f(float x) {
  x = fminf(15.f, fmaxf(-15.f, x));
  float e = __expf(2.f * x);
  return (e - 1.f) / (e + 1.f);
}
__device__ __forceinline__ float sigm_f(float x) { return 1.f / (1.f + __expf(-x)); }
__device__ __forceinline__ float wsum(float v) {
  #pragma unroll
  for (int m = 32; m; m >>= 1) v += __shfl_xor(v, m, 64);
  return v;
}
__device__ __forceinline__ float wmax(float v) {
  #pragma unroll
  for (int m = 32; m; m >>= 1) v = fmaxf(v, __shfl_xor(v, m, 64));
  return v;
}

// ---- MALL-coherent bypass ops (sc0 sc1), non-atomic so they pipeline ----
// Stores: fire-and-forget; drained by the vmcnt(0) in gsync before publish.
__device__ __forceinline__ void bst(float* a, float v) {
  asm volatile("global_store_dword %0, %1, off sc0 sc1" :: "v"(a), "v"(v) : "memory");
}
__device__ __forceinline__ void bst4(float* a, vf4 v) {
  asm volatile("global_store_dwordx4 %0, %1, off sc0 sc1" :: "v"(a), "v"(v) : "memory");
}
// Loads: batched 4 in flight per waitcnt (latency amortized 4x).
__device__ __forceinline__ vf4 bld4(const float* a) {
  vf4 v;
  asm volatile("global_load_dwordx4 %0, %1, off sc0 sc1\n"
               "s_waitcnt vmcnt(0)" : "=v"(v) : "v"(a) : "memory");
  return v;
}
__device__ __forceinline__ void bld4x4(vf4* r, const float* p0, const float* p1,
                                       const float* p2, const float* p3) {
  asm volatile(
    "global_load_dwordx4 %0, %4, off sc0 sc1\n"
    "global_load_dwordx4 %1, %5, off sc0 sc1\n"
    "global_load_dwordx4 %2, %6, off sc0 sc1\n"
    "global_load_dwordx4 %3, %7, off sc0 sc1\n"
    "s_waitcnt vmcnt(0)"
    : "=&v"(r[0]), "=&v"(r[1]), "=&v"(r[2]), "=&v"(r[3])
    : "v"(p0), "v"(p1), "v"(p2), "v"(p3) : "memory");
}

__global__ void __launch_bounds__(NT, 1) condatt_kernel(CAParams p) {
  extern __shared__ float lds[];
  float* wt   = lds + LDS_WT;
  float* zs   = lds + LDS_ZS;
  float* pc   = lds + LDS_PC;
  float* scr  = lds + LDS_SCR;
  float* gld  = lds + LDS_GLD;
  float* aw   = lds + LDS_ATT;
  float* av2  = lds + LDS_ATT + 256;
  float* abv  = lds + LDS_ATT + 512;
  float* araw = lds + LDS_ATT + 768;
  float* asmx = lds + LDS_ATT + 832;
  float* arawZ= lds + LDS_ATT + 896;

  const int tid = threadIdx.x;
  const int wg  = blockIdx.x;
  float* wsp = p.ws;
  unsigned* ctr = (unsigned*)(wsp + WS_CTR);
  unsigned nbar = 0;

  // discard any stale L1/L2 lines from previous blits/dispatches (once per WG)
  __threadfence_system();

  const int kh = tid >> 4, sub = tid & 15, bg = sub >> 2, cp = sub & 3;
  float acc[4][2] = {{0.f,0.f},{0.f,0.f},{0.f,0.f},{0.f,0.f}};
  float hprev = 0.f, cprev = 0.f;  // threads 0..31: per-(b,d) recurrent state

  // Grid barrier: tid0-only relaxed RMW + poll (no cache maintenance, no mass polling).
  auto gsync = [&]() {
    asm volatile("s_waitcnt vmcnt(0)" ::: "memory");
    __syncthreads();
    ++nbar;
    if (tid == 0) {
      __hip_atomic_fetch_add(ctr, 1u, __ATOMIC_RELAXED, __HIP_MEMORY_SCOPE_SYSTEM);
      unsigned tgt = nbar * (unsigned)NWG;
      while (__hip_atomic_load(ctr, __ATOMIC_RELAXED, __HIP_MEMORY_SCOPE_SYSTEM) < tgt)
        __builtin_amdgcn_s_sleep(4);
    }
    __syncthreads();
  };

  // ---------------- prologue ----------------
  {
    // ctx_trans = context @ att_ctx_W1 + att_b1 : 4 (b,l)-rows per wg
    for (int j = 0; j < 4; ++j) {
      int rid = wg * 4 + j;  // rid = b*64 + l
      __syncthreads();
      for (int i = tid; i < 512; i += NT) scr[i] = p.ctx[rid * 512 + i];
      __syncthreads();
      float a0 = 0.f, a1 = 0.f, a2 = 0.f, a3 = 0.f;
      for (int c = 0; c < 512; c += 4) {
        a0 += scr[c+0] * p.acW1[(c+0) * 256 + tid];
        a1 += scr[c+1] * p.acW1[(c+1) * 256 + tid];
        a2 += scr[c+2] * p.acW1[(c+2) * 256 + tid];
        a3 += scr[c+3] * p.acW1[(c+3) * 256 + tid];
      }
      bst(wsp + WS_CT + rid * 256 + tid, p.ab1[tid] + ((a0 + a1) + (a2 + a3)));
    }
    __syncthreads();
    // persistent gate-GEMM weights: K rows 0..511=Wx,512..=U,P,C,H; col-pair interleaved per cp
    const float* mats[5] = {p.Wx, p.U, p.P, p.C, p.H};
    for (int i = tid; i < 8 * 2560; i += NT) {
      int c = i / 2560, r = i - c * 2560;
      int m = r >> 9, rr = r & 511;
      int n = 2 * wg + (c >> 2) + 512 * (c & 3);
      wt[(c >> 1) * 5136 + r * 2 + (c & 1)] = mats[m][rr * 2048 + n];
    }
    // persistent projection columns (col = wg) of att_h_W1, hatt_h_W1, hatt_hist_W
    const float* pm[3] = {p.ahW1, p.hthW1, p.hhW};
    for (int i = tid; i < 3 * 512; i += NT) {
      int m = i >> 9, d = i & 511;
      pc[i] = pm[m][d * 256 + wg];
    }
    // stage X(0) and do the x-part GEMM before the loop
    #pragma unroll
    for (int j = 0; j < 8; ++j) {
      int i4 = tid + j * NT, b = i4 >> 7, k0 = (i4 << 2) & 511;
      vf4 v = *(const vf4*)(p.X + (b * 64 + 0) * 512 + k0);
      *(vf4*)(zs + b * 516 + k0) = v;
    }
    __syncthreads();
  }

  auto gemm = [&](int comp) {
    const float* wp = wt + cp * 5136 + comp * 1024;
    const float* zb = zs + (bg * 4) * 516;
    #pragma unroll 4
    for (int j = 0; j < 32; ++j) {
      int k = kh + (j << 4);
      vf2 w = *(const vf2*)(wp + k * 2);
      float z0 = zb[k], z1 = zb[516 + k], z2 = zb[1032 + k], z3 = zb[1548 + k];
      acc[0][0] += z0 * w.x; acc[0][1] += z0 * w.y;
      acc[1][0] += z1 * w.x; acc[1][1] += z1 * w.y;
      acc[2][0] += z2 * w.x; acc[2][1] += z2 * w.y;
      acc[3][0] += z3 * w.x; acc[3][1] += z3 * w.y;
    }
  };

  gemm(0);  // x-part for t=0

  for (int t = 0; t < 64; ++t) {
    // ---- P0: stage h (=HIST row t-1, cached), proj, par gather, gate-GEMM h/par parts ----
    __syncthreads();
    if (t == 0) {
      vf4 z = {0.f, 0.f, 0.f, 0.f};
      #pragma unroll
      for (int j = 0; j < 8; ++j) {
        int i4 = tid + j * NT, b = i4 >> 7, k0 = (i4 << 2) & 511;
        *(vf4*)(zs + b * 516 + k0) = z;
      }
    } else {
      #pragma unroll
      for (int j = 0; j < 8; ++j) {
        int i4 = tid + j * NT, b = i4 >> 7, k0 = (i4 << 2) & 511;
        vf4 v = *(const vf4*)(wsp + WS_HIST + (b * 64 + (t - 1)) * 512 + k0);
        *(vf4*)(zs + b * 516 + k0) = v;
      }
    }
    __syncthreads();
    gemm(1);
    {
      int w = tid >> 6, lane = tid & 63;
      for (int j = w * 12; j < w * 12 + 12; ++j) {
        int m = j >> 4, b = j & 15;
        float s = 0.f;
        #pragma unroll
        for (int e = 0; e < 8; ++e) { int k = lane + (e << 6); s += zs[b * 516 + k] * pc[m * 512 + k]; }
        s = wsum(s);
        if (lane == 0) {
          if (m == 0)      bst(wsp + WS_HW1  + b * 256 + wg, s);
          else if (m == 1) bst(wsp + WS_HW1H + b * 256 + wg, s);
          else if (t > 0)  bst(wsp + WS_CACHE + (b * 64 + (t - 1)) * 256 + wg, s);
        }
      }
    }
    __syncthreads();
    {
      #pragma unroll
      for (int j = 0; j < 8; ++j) {
        int i4 = tid + j * NT, b = i4 >> 7, k0 = (i4 << 2) & 511;
        int par = p.parent[b * 64 + t];
        vf4 v = {0.f, 0.f, 0.f, 0.f};
        if (t > 0 && par < t) v = *(const vf4*)(wsp + WS_HIST + (b * 64 + par) * 512 + k0);
        *(vf4*)(zs + b * 516 + k0) = v;
      }
    }
    __syncthreads();
    gemm(2);
    gsync();

    // ---- P1: attention (wg 0..15 ctx-att b=wg; wg 16..31 hist-att b=wg-16) ----
    if (wg < 16) {
      const int b = wg;
      if (tid < 64) { vf4 v = bld4(wsp + WS_HW1 + b * 256 + tid * 4); *(vf4*)(aw + tid * 4) = v; }
      av2[tid] = p.aW2[tid];
      __syncthreads();
      {
        int w = tid >> 6, lane = tid & 63;
        float b2 = *p.ab2;
        for (int l = w; l < 64; l += 4) {
          float s = 0.f;
          #pragma unroll
          for (int q = 0; q < 4; ++q) { int a = lane + (q << 6); s += av2[a] * tanh_f(wsp[WS_CT + (b * 64 + l) * 256 + a] + aw[a]); }
          s = wsum(s) + b2;
          if (lane == 0) araw[l] = (p.cmask[b * 64 + l] > 0) ? -INFINITY : s;
        }
      }
      __syncthreads();
      if (tid < 64) {
        float r = araw[tid];
        float mx = wmax(r);
        float e = __expf(r - mx);
        float sm = wsum(e);
        asmx[tid] = e / sm;
      }
      __syncthreads();
      if (tid < 128) {
        vf4 a0 = {0.f, 0.f, 0.f, 0.f};
        #pragma unroll 8
        for (int l = 0; l < 64; ++l) {
          float ca = asmx[l];
          vf4 cv = *(const vf4*)(p.ctx + (b * 64 + l) * 512 + tid * 4);
          a0.x += ca * cv.x; a0.y += ca * cv.y; a0.z += ca * cv.z; a0.w += ca * cv.w;
        }
        bst4(p.out + OUT_CTX + (b * 64 + t) * 512 + tid * 4, a0);
      }
    } else if (wg < 32) {
      const int b = wg - 16;
      if (tid < 64) { vf4 v = bld4(wsp + WS_HW1H + b * 256 + tid * 4); *(vf4*)(aw + tid * 4) = v; }
      av2[tid] = p.hW2[tid]; abv[tid] = p.hhb[tid];
      __syncthreads();
      {
        int w = tid >> 6, lane = tid & 63;
        float b2 = *p.hb2;
        for (int l = w; l < t; l += 4) {
          float s = 0.f;
          #pragma unroll
          for (int q = 0; q < 4; ++q) { int a = lane + (q << 6); s += av2[a] * tanh_f(wsp[WS_CACHE + (b * 64 + l) * 256 + a] + abv[a] + aw[a]); }
          s = wsum(s) + b2;
          if (lane == 0) araw[l] = s;
        }
        if (w == 0) {  // raw value for unwritten hist rows (hist row = 0 in reference)
          float s = 0.f;
          #pragma unroll
          for (int q = 0; q < 4; ++q) { int a = lane + (q << 6); s += av2[a] * tanh_f(abv[a] + aw[a]); }
          s = wsum(s) + b2;
          if (lane == 0) arawZ[0] = s;
        }
      }
      __syncthreads();
      if (tid < 64) {
        float r = (tid < t) ? araw[tid] : arawZ[0];
        float mx = wmax(r);                    // max over ALL t' (matches reference)
        float e = (tid < t) ? __expf(r - mx) : 0.f;
        float sm = wsum(e);
        asmx[tid] = e / (sm + 1e-7f);
      }
      __syncthreads();
      if (tid < 128) {
        vf4 a0 = {0.f, 0.f, 0.f, 0.f};
        #pragma unroll 4
        for (int l = 0; l < t; ++l) {
          float hv = asmx[l];
          vf4 hvv = *(const vf4*)(wsp + WS_HIST + (b * 64 + l) * 512 + tid * 4);
          a0.x += hv * hvv.x; a0.y += hv * hvv.y; a0.z += hv * hvv.z; a0.w += hv * hvv.w;
        }
        bst4(wsp + WS_HC + b * 512 + tid * 4, a0);
      }
    }
    gsync();

    // ---- P2: + cv@C + hc@H, reduce, gates; then pre-stage X(t+1) + x-GEMM ----
    {
      #pragma unroll
      for (int j = 0; j < 8; ++j) {  // stage ctx_vec from out (cached, first-touch-after-write)
        int i4 = tid + j * NT, b = i4 >> 7, k0 = (i4 << 2) & 511;
        vf4 v = *(const vf4*)(p.out + OUT_CTX + (b * 64 + t) * 512 + k0);
        *(vf4*)(zs + b * 516 + k0) = v;
      }
    }
    __syncthreads();
    gemm(3);
    __syncthreads();
    {
      vf4 r[4];
      #pragma unroll
      for (int h2 = 0; h2 < 2; ++h2) {  // stage h_ctx (bypass, batched)
        int i0 = tid + (h2*4+0)*NT, i1 = tid + (h2*4+1)*NT, i2 = tid + (h2*4+2)*NT, i3 = tid + (h2*4+3)*NT;
        bld4x4(r,
               wsp + WS_HC + (i0 >> 7) * 512 + ((i0 << 2) & 511),
               wsp + WS_HC + (i1 >> 7) * 512 + ((i1 << 2) & 511),
               wsp + WS_HC + (i2 >> 7) * 512 + ((i2 << 2) & 511),
               wsp + WS_HC + (i3 >> 7) * 512 + ((i3 << 2) & 511));
        *(vf4*)(zs + (i0 >> 7) * 516 + ((i0 << 2) & 511)) = r[0];
        *(vf4*)(zs + (i1 >> 7) * 516 + ((i1 << 2) & 511)) = r[1];
        *(vf4*)(zs + (i2 >> 7) * 516 + ((i2 << 2) & 511)) = r[2];
        *(vf4*)(zs + (i3 >> 7) * 516 + ((i3 << 2) & 511)) = r[3];
      }
    }
    __syncthreads();
    gemm(4);
    {
      float* s8 = scr + (kh * 16 + sub) * 8;
      #pragma unroll
      for (int i = 0; i < 4; ++i) { s8[i*2] = acc[i][0]; s8[i*2+1] = acc[i][1]; acc[i][0] = 0.f; acc[i][1] = 0.f; }
    }
    __syncthreads();
    if (t < 63) {
      #pragma unroll
      for (int j = 0; j < 8; ++j) {  // pre-stage X(t+1)
        int i4 = tid + j * NT, b = i4 >> 7, k0 = (i4 << 2) & 511;
        vf4 v = *(const vf4*)(p.X + (b * 64 + (t + 1)) * 512 + k0);
        *(vf4*)(zs + b * 516 + k0) = v;
      }
    }
    if (tid < 128) {
      int b = tid >> 3, c = tid & 7;
      int n = 2 * wg + (c >> 2) + 512 * (c & 3);
      float g = p.bx[n];
      int sidx = (b >> 2) * 4 + (c >> 1);
      int aidx = (b & 3) * 2 + (c & 1);
      #pragma unroll
      for (int k2 = 0; k2 < 16; ++k2) g += scr[(k2 * 16 + sidx) * 8 + aidx];
      gld[b * 8 + c] = g;
    }
    __syncthreads();
    if (tid < 32) {
      int b = tid >> 1, dj = tid & 1;
      int d = 2 * wg + dj;
      float gi = gld[b*8 + dj*4 + 0];
      float gf = gld[b*8 + dj*4 + 1];
      float gg = gld[b*8 + dj*4 + 2];
      float go = gld[b*8 + dj*4 + 3];
      float i_ = sigm_f(gi), f_ = sigm_f(go * 0.f + gf), o_ = sigm_f(go);
      float cn = f_ * cprev + i_ * tanh_f(gg);
      float hn = o_ * tanh_f(cn);
      float m_ = p.mask[b * 64 + t];
      hn = (1.f - m_) * hprev + m_ * hn;
      cn = (1.f - m_) * cprev + m_ * cn;
      hprev = hn; cprev = cn;
      bst(wsp + WS_HIST + (b * 64 + t) * 512 + d, hn);
      p.out[OUT_HS + (b * 64 + t) * 512 + d] = hn;
      p.out[OUT_CS + (b * 64 + t) * 512 + d] = cn;
    }
    if (t < 63) {
      gemm(0);   // x-part for t+1 (zs holds X(t+1))
      gsync();
    }
  }
}

extern "C" void kernel_launch(void* const* d_in, const int* in_sizes, int n_in,
                              void* d_out, int out_size, void* d_ws, size_t ws_size,
                              hipStream_t stream) {
  CAParams p;
  p.X      = (const float*)d_in[0];
  p.ctx    = (const float*)d_in[1];
  p.parent = (const int*)  d_in[2];
  p.cmask  = (const int*)  d_in[3];
  p.mask   = (const float*)d_in[4];
  p.Wx = (const float*)d_in[5];  p.bx = (const float*)d_in[6];
  p.U  = (const float*)d_in[7];  p.C  = (const float*)d_in[8];
  p.P  = (const float*)d_in[9];  p.H  = (const float*)d_in[10];
  p.acW1 = (const float*)d_in[11]; p.ab1 = (const float*)d_in[12];
  p.ahW1 = (const float*)d_in[13]; p.aW2 = (const float*)d_in[14]; p.ab2 = (const float*)d_in[15];
  p.hhW  = (const float*)d_in[16]; p.hhb = (const float*)d_in[17];
  p.hthW1= (const float*)d_in[18]; p.hW2 = (const float*)d_in[19]; p.hb2 = (const float*)d_in[20];
  p.out = (float*)d_out;
  p.ws  = (float*)d_ws;

  // reset barrier counter (monotonic within a dispatch; restarts each launch)
  (void)hipMemsetAsync((char*)d_ws + (size_t)WS_CTR * sizeof(float), 0, 1024, stream);

  static_assert(LDS_FLOATS * 4 <= 160 * 1024, "LDS budget");
  (void)hipFuncSetAttribute((const void*)condatt_kernel,
                      hipFuncAttributeMaxDynamicSharedMemorySize, LDS_FLOATS * 4);
  hipLaunchKernelGGL(condatt_kernel, dim3(NWG), dim3(NT), LDS_FLOATS * 4, stream, p);
}

// Round 5
// 3359.155 us; speedup vs baseline: 1.7977x; 1.0905x over previous
//
#include <hip/hip_runtime.h>
#include <cmath>

#define NWG 256
#define NT  256

// dims: B=16, T=64, L=64, D=512, A=256, 4D=2048
// ws float offsets
#define WS_HW1   0         // 16*256   (h@att_h_W1, rewritten per step; bypass-only)
#define WS_HW1H  4096      // 16*256   (h@hatt_h_W1, bypass-only)
#define WS_HC    8192      // 16*512   (h_ctx, bypass-only)
#define WS_CT    16384     // 16*64*256 ctx_trans (write-once prologue, cached reads)
#define WS_CACHE 278528    // 16*64*256 hist@hatt_hist_W rows (write-once per row, cached reads)
#define WS_HIST  540672    // 16*64*512 h history rows (write-once per row, cached reads)
#define WS_CTR   1064960   // u32 barrier counter (reset each launch)

// out float offsets (hs | cs | ctxs)
#define OUT_HS  0
#define OUT_CS  524288
#define OUT_CTX 1048576

// lds float offsets
#define LDS_WT   0        // 4 quarters x 5136 (2560 K rows * 2 cols interleaved + pad)
#define LDS_ZS   20544    // z-stage [16 b][516]
#define LDS_PC   28800    // 3 proj cols x 512
#define LDS_SCR  30336    // scratch 2048 floats (gemm reduce / einsum partials)
#define LDS_GLD  32384    // g lds 16*8
#define LDS_ATT  32512    // aw 256 | av2 256 | abv 256 | araw 64 | asmx 64 | arawZ 64
#define LDS_FLOATS 33472  // *4 = 133,888 B < 160 KB

typedef float vf4 __attribute__((ext_vector_type(4)));
typedef float vf2 __attribute__((ext_vector_type(2)));

struct CAParams {
  const float* X; const float* ctx; const int* parent; const int* cmask; const float* mask;
  const float* Wx; const float* bx; const float* U; const float* C; const float* P; const float* H;
  const float* acW1; const float* ab1; const float* ahW1; const float* aW2; const float* ab2;
  const float* hhW; const float* hhb; const float* hthW1; const float* hW2; const float* hb2;
  float* out; float* ws;
};

__device__ __forceinline__ float tanh_f(float x) {
  x = fminf(15.f, fmaxf(-15.f, x));
  float e = __expf(2.f * x);
  return (e - 1.f) / (e + 1.f);
}
__device__ __forceinline__ float sigm_f(float x) { return 1.f / (1.f + __expf(-x)); }
__device__ __forceinline__ float wsum(float v) {
  #pragma unroll
  for (int m = 32; m; m >>= 1) v += __shfl_xor(v, m, 64);
  return v;
}
__device__ __forceinline__ float wmax(float v) {
  #pragma unroll
  for (int m = 32; m; m >>= 1) v = fmaxf(v, __shfl_xor(v, m, 64));
  return v;
}
__device__ __forceinline__ float hsum32(float v) {  // reduce within 32-lane half
  #pragma unroll
  for (int m = 16; m; m >>= 1) v += __shfl_xor(v, m, 64);
  return v;
}

// ---- MALL-coherent bypass ops (sc0 sc1), non-atomic so they pipeline ----
__device__ __forceinline__ void bst(float* a, float v) {
  asm volatile("global_store_dword %0, %1, off sc0 sc1" :: "v"(a), "v"(v) : "memory");
}
__device__ __forceinline__ void bst4(float* a, vf4 v) {
  asm volatile("global_store_dwordx4 %0, %1, off sc0 sc1" :: "v"(a), "v"(v) : "memory");
}
__device__ __forceinline__ vf4 bld4(const float* a) {
  vf4 v;
  asm volatile("global_load_dwordx4 %0, %1, off sc0 sc1\n"
               "s_waitcnt vmcnt(0)" : "=v"(v) : "v"(a) : "memory");
  return v;
}
__device__ __forceinline__ void bld4x4(vf4* r, const float* p0, const float* p1,
                                       const float* p2, const float* p3) {
  asm volatile(
    "global_load_dwordx4 %0, %4, off sc0 sc1\n"
    "global_load_dwordx4 %1, %5, off sc0 sc1\n"
    "global_load_dwordx4 %2, %6, off sc0 sc1\n"
    "global_load_dwordx4 %3, %7, off sc0 sc1\n"
    "s_waitcnt vmcnt(0)"
    : "=&v"(r[0]), "=&v"(r[1]), "=&v"(r[2]), "=&v"(r[3])
    : "v"(p0), "v"(p1), "v"(p2), "v"(p3) : "memory");
}

__global__ void __launch_bounds__(NT, 1) condatt_kernel(CAParams p) {
  extern __shared__ float lds[];
  float* wt   = lds + LDS_WT;
  float* zs   = lds + LDS_ZS;
  float* pc   = lds + LDS_PC;
  float* scr  = lds + LDS_SCR;
  float* gld  = lds + LDS_GLD;
  float* aw   = lds + LDS_ATT;
  float* av2  = lds + LDS_ATT + 256;
  float* abv  = lds + LDS_ATT + 512;
  float* araw = lds + LDS_ATT + 768;
  float* asmx = lds + LDS_ATT + 832;
  float* arawZ= lds + LDS_ATT + 896;

  const int tid = threadIdx.x;
  const int wg  = blockIdx.x;
  float* wsp = p.ws;
  unsigned* ctr = (unsigned*)(wsp + WS_CTR);
  unsigned nbar = 0;

  // XCD-contiguous column assignment: WGs co-resident on an XCD (wg%8 equal)
  // own contiguous column blocks -> weight cache lines fully consumed per XCD.
  const int base = 2 * ((wg & 7) * 32 + (wg >> 3));  // gate col pair {base, base+1}
  const int pcol = base >> 1;                        // projection column

  // discard any stale L1/L2 lines from previous blits/dispatches (once per WG)
  __threadfence_system();

  const int kh = tid >> 4, sub = tid & 15, bg = sub >> 2, cp = sub & 3;
  float acc[4][2] = {{0.f,0.f},{0.f,0.f},{0.f,0.f},{0.f,0.f}};
  float hprev = 0.f, cprev = 0.f;  // threads 0..31: per-(b,d) recurrent state

  auto gsync = [&]() {
    asm volatile("s_waitcnt vmcnt(0)" ::: "memory");
    __syncthreads();
    ++nbar;
    if (tid == 0) {
      __hip_atomic_fetch_add(ctr, 1u, __ATOMIC_RELAXED, __HIP_MEMORY_SCOPE_SYSTEM);
      unsigned tgt = nbar * (unsigned)NWG;
      while (__hip_atomic_load(ctr, __ATOMIC_RELAXED, __HIP_MEMORY_SCOPE_SYSTEM) < tgt)
        __builtin_amdgcn_s_sleep(4);
    }
    __syncthreads();
  };

  // ---------------- prologue ----------------
  {
    // ctx_trans = context @ att_ctx_W1 + att_b1 : 4 (b,l)-rows per wg
    for (int j = 0; j < 4; ++j) {
      int rid = wg * 4 + j;  // rid = b*64 + l
      __syncthreads();
      for (int i = tid; i < 512; i += NT) scr[i] = p.ctx[rid * 512 + i];
      __syncthreads();
      float a0 = 0.f, a1 = 0.f, a2 = 0.f, a3 = 0.f;
      for (int c = 0; c < 512; c += 4) {
        a0 += scr[c+0] * p.acW1[(c+0) * 256 + tid];
        a1 += scr[c+1] * p.acW1[(c+1) * 256 + tid];
        a2 += scr[c+2] * p.acW1[(c+2) * 256 + tid];
        a3 += scr[c+3] * p.acW1[(c+3) * 256 + tid];
      }
      bst(wsp + WS_CT + rid * 256 + tid, p.ab1[tid] + ((a0 + a1) + (a2 + a3)));
    }
    __syncthreads();
    // persistent gate-GEMM weights: quarter q (of 4), cols (base, base+1), K rows
    // 0..511=Wx, 512..1023=U, 1024..1535=P, 1536..2047=C, 2048..2559=H.
    // LDS c-index = q*2 + oo  ->  global n = base + oo + 512*q.
    const float* mats[5] = {p.Wx, p.U, p.P, p.C, p.H};
    for (int q = 0; q < 4; ++q) {
      for (int r = tid; r < 2560; r += NT) {
        int m = r >> 9, rr = r & 511;
        vf2 v = *(const vf2*)(mats[m] + rr * 2048 + base + 512 * q);
        *(vf2*)(wt + q * 5136 + r * 2) = v;
      }
    }
    // persistent projection column pcol of att_h_W1, hatt_h_W1, hatt_hist_W
    const float* pm[3] = {p.ahW1, p.hthW1, p.hhW};
    for (int i = tid; i < 3 * 512; i += NT) {
      int m = i >> 9, d = i & 511;
      pc[i] = pm[m][d * 256 + pcol];
    }
    // stage X(0) and do the x-part GEMM before the loop
    #pragma unroll
    for (int j = 0; j < 8; ++j) {
      int i4 = tid + j * NT, b = i4 >> 7, k0 = (i4 << 2) & 511;
      vf4 v = *(const vf4*)(p.X + (b * 64 + 0) * 512 + k0);
      *(vf4*)(zs + b * 516 + k0) = v;
    }
    __syncthreads();
  }

  auto gemm = [&](int comp) {
    const float* wp = wt + cp * 5136 + comp * 1024;
    const float* zb = zs + (bg * 4) * 516;
    #pragma unroll 4
    for (int j = 0; j < 32; ++j) {
      int k = kh + (j << 4);
      vf2 w = *(const vf2*)(wp + k * 2);
      float z0 = zb[k], z1 = zb[516 + k], z2 = zb[1032 + k], z3 = zb[1548 + k];
      acc[0][0] += z0 * w.x; acc[0][1] += z0 * w.y;
      acc[1][0] += z1 * w.x; acc[1][1] += z1 * w.y;
      acc[2][0] += z2 * w.x; acc[2][1] += z2 * w.y;
      acc[3][0] += z3 * w.x; acc[3][1] += z3 * w.y;
    }
  };

  gemm(0);  // x-part for t=0

  for (int t = 0; t < 64; ++t) {
    // ---- P0: stage h (=HIST row t-1, cached), proj, par gather, gate-GEMM h/par parts ----
    __syncthreads();
    if (t == 0) {
      vf4 z = {0.f, 0.f, 0.f, 0.f};
      #pragma unroll
      for (int j = 0; j < 8; ++j) {
        int i4 = tid + j * NT, b = i4 >> 7, k0 = (i4 << 2) & 511;
        *(vf4*)(zs + b * 516 + k0) = z;
      }
    } else {
      #pragma unroll
      for (int j = 0; j < 8; ++j) {
        int i4 = tid + j * NT, b = i4 >> 7, k0 = (i4 << 2) & 511;
        vf4 v = *(const vf4*)(wsp + WS_HIST + (b * 64 + (t - 1)) * 512 + k0);
        *(vf4*)(zs + b * 516 + k0) = v;
      }
    }
    __syncthreads();
    gemm(1);
    {
      int w = tid >> 6, lane = tid & 63;
      for (int j = w * 12; j < w * 12 + 12; ++j) {
        int m = j >> 4, b = j & 15;
        float s = 0.f;
        #pragma unroll
        for (int e = 0; e < 8; ++e) { int k = lane + (e << 6); s += zs[b * 516 + k] * pc[m * 512 + k]; }
        s = wsum(s);
        if (lane == 0) {
          if (m == 0)      bst(wsp + WS_HW1  + b * 256 + pcol, s);
          else if (m == 1) bst(wsp + WS_HW1H + b * 256 + pcol, s);
          else if (t > 0)  bst(wsp + WS_CACHE + (b * 64 + (t - 1)) * 256 + pcol, s);
        }
      }
    }
    __syncthreads();
    {
      #pragma unroll
      for (int j = 0; j < 8; ++j) {
        int i4 = tid + j * NT, b = i4 >> 7, k0 = (i4 << 2) & 511;
        int par = p.parent[b * 64 + t];
        vf4 v = {0.f, 0.f, 0.f, 0.f};
        if (t > 0 && par < t) v = *(const vf4*)(wsp + WS_HIST + (b * 64 + par) * 512 + k0);
        *(vf4*)(zs + b * 516 + k0) = v;
      }
    }
    __syncthreads();
    gemm(2);
    gsync();

    // ---- P1: attention (wg 0..15 ctx-att b=wg; wg 16..31 hist-att b=wg-16) ----
    if (wg < 16) {
      const int b = wg;
      if (tid < 64) { vf4 v = bld4(wsp + WS_HW1 + b * 256 + tid * 4); *(vf4*)(aw + tid * 4) = v; }
      av2[tid] = p.aW2[tid];
      __syncthreads();
      {
        // half-wave per l-row: 8 rows in flight across 4 waves
        int w = tid >> 6, s32 = tid & 31, hi = (tid >> 5) & 1;
        float b2 = *p.ab2;
        for (int l = w * 2 + hi; l < 64; l += 8) {
          float s = 0.f;
          #pragma unroll
          for (int q = 0; q < 8; ++q) { int a = s32 + (q << 5); s += av2[a] * tanh_f(wsp[WS_CT + (b * 64 + l) * 256 + a] + aw[a]); }
          s = hsum32(s) + b2;
          if (s32 == 0) araw[l] = (p.cmask[b * 64 + l] > 0) ? -INFINITY : s;
        }
      }
      __syncthreads();
      if (tid < 64) {
        float r = araw[tid];
        float mx = wmax(r);
        float e = __expf(r - mx);
        float sm = wsum(e);
        asmx[tid] = e / sm;
      }
      __syncthreads();
      {
        // einsum over l: all 256 threads, 2-way l-split + LDS partial reduce
        int db = tid & 127, half = tid >> 7;
        vf4 a0 = {0.f, 0.f, 0.f, 0.f};
        #pragma unroll 4
        for (int l = half; l < 64; l += 2) {
          float ca = asmx[l];
          vf4 cv = *(const vf4*)(p.ctx + (b * 64 + l) * 512 + db * 4);
          a0.x += ca * cv.x; a0.y += ca * cv.y; a0.z += ca * cv.z; a0.w += ca * cv.w;
        }
        *(vf4*)(scr + tid * 4) = a0;
      }
      __syncthreads();
      if (tid < 128) {
        vf4 u = *(vf4*)(scr + tid * 4), v = *(vf4*)(scr + (tid + 128) * 4);
        u.x += v.x; u.y += v.y; u.z += v.z; u.w += v.w;
        bst4(p.out + OUT_CTX + (b * 64 + t) * 512 + tid * 4, u);
      }
    } else if (wg < 32) {
      const int b = wg - 16;
      if (tid < 64) { vf4 v = bld4(wsp + WS_HW1H + b * 256 + tid * 4); *(vf4*)(aw + tid * 4) = v; }
      av2[tid] = p.hW2[tid]; abv[tid] = p.hhb[tid];
      __syncthreads();
      {
        int w = tid >> 6, s32 = tid & 31, hi = (tid >> 5) & 1;
        float b2 = *p.hb2;
        for (int l = w * 2 + hi; l < t; l += 8) {
          float s = 0.f;
          #pragma unroll
          for (int q = 0; q < 8; ++q) { int a = s32 + (q << 5); s += av2[a] * tanh_f(wsp[WS_CACHE + (b * 64 + l) * 256 + a] + abv[a] + aw[a]); }
          s = hsum32(s) + b2;
          if (s32 == 0) araw[l] = s;
        }
        if (tid < 32) {  // raw value for unwritten hist rows (hist row = 0 in reference)
          float s = 0.f;
          #pragma unroll
          for (int q = 0; q < 8; ++q) { int a = tid + (q << 5); s += av2[a] * tanh_f(abv[a] + aw[a]); }
          s = hsum32(s) + b2;
          if (tid == 0) arawZ[0] = s;
        }
      }
      __syncthreads();
      if (tid < 64) {
        float r = (tid < t) ? araw[tid] : arawZ[0];
        float mx = wmax(r);                    // max over ALL t' (matches reference)
        float e = (tid < t) ? __expf(r - mx) : 0.f;
        float sm = wsum(e);
        asmx[tid] = e / (sm + 1e-7f);
      }
      __syncthreads();
      {
        int db = tid & 127, half = tid >> 7;
        vf4 a0 = {0.f, 0.f, 0.f, 0.f};
        #pragma unroll 4
        for (int l = half; l < t; l += 2) {
          float hv = asmx[l];
          vf4 hvv = *(const vf4*)(wsp + WS_HIST + (b * 64 + l) * 512 + db * 4);
          a0.x += hv * hvv.x; a0.y += hv * hvv.y; a0.z += hv * hvv.z; a0.w += hv * hvv.w;
        }
        *(vf4*)(scr + tid * 4) = a0;
      }
      __syncthreads();
      if (tid < 128) {
        vf4 u = *(vf4*)(scr + tid * 4), v = *(vf4*)(scr + (tid + 128) * 4);
        u.x += v.x; u.y += v.y; u.z += v.z; u.w += v.w;
        bst4(wsp + WS_HC + b * 512 + tid * 4, u);
      }
    }
    gsync();

    // ---- P2: + cv@C + hc@H, reduce, gates; then pre-stage X(t+1) + x-GEMM ----
    {
      #pragma unroll
      for (int j = 0; j < 8; ++j) {  // stage ctx_vec from out (cached, first-touch-after-write)
        int i4 = tid + j * NT, b = i4 >> 7, k0 = (i4 << 2) & 511;
        vf4 v = *(const vf4*)(p.out + OUT_CTX + (b * 64 + t) * 512 + k0);
        *(vf4*)(zs + b * 516 + k0) = v;
      }
    }
    __syncthreads();
    gemm(3);
    __syncthreads();
    {
      vf4 r[4];
      #pragma unroll
      for (int h2 = 0; h2 < 2; ++h2) {  // stage h_ctx (bypass, batched)
        int i0 = tid + (h2*4+0)*NT, i1 = tid + (h2*4+1)*NT, i2 = tid + (h2*4+2)*NT, i3 = tid + (h2*4+3)*NT;
        bld4x4(r,
               wsp + WS_HC + (i0 >> 7) * 512 + ((i0 << 2) & 511),
               wsp + WS_HC + (i1 >> 7) * 512 + ((i1 << 2) & 511),
               wsp + WS_HC + (i2 >> 7) * 512 + ((i2 << 2) & 511),
               wsp + WS_HC + (i3 >> 7) * 512 + ((i3 << 2) & 511));
        *(vf4*)(zs + (i0 >> 7) * 516 + ((i0 << 2) & 511)) = r[0];
        *(vf4*)(zs + (i1 >> 7) * 516 + ((i1 << 2) & 511)) = r[1];
        *(vf4*)(zs + (i2 >> 7) * 516 + ((i2 << 2) & 511)) = r[2];
        *(vf4*)(zs + (i3 >> 7) * 516 + ((i3 << 2) & 511)) = r[3];
      }
    }
    __syncthreads();
    gemm(4);
    {
      float* s8 = scr + (kh * 16 + sub) * 8;
      #pragma unroll
      for (int i = 0; i < 4; ++i) { s8[i*2] = acc[i][0]; s8[i*2+1] = acc[i][1]; acc[i][0] = 0.f; acc[i][1] = 0.f; }
    }
    __syncthreads();
    if (t < 63) {
      #pragma unroll
      for (int j = 0; j < 8; ++j) {  // pre-stage X(t+1)
        int i4 = tid + j * NT, b = i4 >> 7, k0 = (i4 << 2) & 511;
        vf4 v = *(const vf4*)(p.X + (b * 64 + (t + 1)) * 512 + k0);
        *(vf4*)(zs + b * 516 + k0) = v;
      }
    }
    if (tid < 128) {
      int b = tid >> 3, c = tid & 7;  // c = quarter*2 + coloff
      int n = base + (c & 1) + 512 * (c >> 1);
      float g = p.bx[n];
      int sidx = (b >> 2) * 4 + (c >> 1);
      int aidx = (b & 3) * 2 + (c & 1);
      #pragma unroll
      for (int k2 = 0; k2 < 16; ++k2) g += scr[(k2 * 16 + sidx) * 8 + aidx];
      gld[b * 8 + c] = g;
    }
    __syncthreads();
    if (tid < 32) {
      int b = tid >> 1, dj = tid & 1;
      int d = base + dj;
      float gi = gld[b*8 + 0 + dj];
      float gf = gld[b*8 + 2 + dj];
      float gg = gld[b*8 + 4 + dj];
      float go = gld[b*8 + 6 + dj];
      float i_ = sigm_f(gi), f_ = sigm_f(gf), o_ = sigm_f(go);
      float cn = f_ * cprev + i_ * tanh_f(gg);
      float hn = o_ * tanh_f(cn);
      float m_ = p.mask[b * 64 + t];
      hn = (1.f - m_) * hprev + m_ * hn;
      cn = (1.f - m_) * cprev + m_ * cn;
      hprev = hn; cprev = cn;
      bst(wsp + WS_HIST + (b * 64 + t) * 512 + d, hn);
      p.out[OUT_HS + (b * 64 + t) * 512 + d] = hn;
      p.out[OUT_CS + (b * 64 + t) * 512 + d] = cn;
    }
    if (t < 63) {
      gemm(0);   // x-part for t+1 (zs holds X(t+1))
      gsync();
    }
  }
}

extern "C" void kernel_launch(void* const* d_in, const int* in_sizes, int n_in,
                              void* d_out, int out_size, void* d_ws, size_t ws_size,
                              hipStream_t stream) {
  CAParams p;
  p.X      = (const float*)d_in[0];
  p.ctx    = (const float*)d_in[1];
  p.parent = (const int*)  d_in[2];
  p.cmask  = (const int*)  d_in[3];
  p.mask   = (const float*)d_in[4];
  p.Wx = (const float*)d_in[5];  p.bx = (const float*)d_in[6];
  p.U  = (const float*)d_in[7];  p.C  = (const float*)d_in[8];
  p.P  = (const float*)d_in[9];  p.H  = (const float*)d_in[10];
  p.acW1 = (const float*)d_in[11]; p.ab1 = (const float*)d_in[12];
  p.ahW1 = (const float*)d_in[13]; p.aW2 = (const float*)d_in[14]; p.ab2 = (const float*)d_in[15];
  p.hhW  = (const float*)d_in[16]; p.hhb = (const float*)d_in[17];
  p.hthW1= (const float*)d_in[18]; p.hW2 = (const float*)d_in[19]; p.hb2 = (const float*)d_in[20];
  p.out = (float*)d_out;
  p.ws  = (float*)d_ws;

  // reset barrier counter (monotonic within a dispatch; restarts each launch)
  (void)hipMemsetAsync((char*)d_ws + (size_t)WS_CTR * sizeof(float), 0, 1024, stream);

  static_assert(LDS_FLOATS * 4 <= 160 * 1024, "LDS budget");
  (void)hipFuncSetAttribute((const void*)condatt_kernel,
                      hipFuncAttributeMaxDynamicSharedMemorySize, LDS_FLOATS * 4);
  hipLaunchKernelGGL(condatt_kernel, dim3(NWG), dim3(NT), LDS_FLOATS * 4, stream, p);
}

// Round 6
// 2266.466 us; speedup vs baseline: 2.6644x; 1.4821x over previous
//
#include <hip/hip_runtime.h>
#include <cmath>

#define NWG 256
#define NT  256

// dims: B=16, T=64, L=64, D=512, A=256, 4D=2048
// ws float offsets
#define WS_FLAGS 0         // u32 flags[256] @ 64B stride (4096 floats = 16 KB)
#define WS_HC    8192      // 16*512   (h_ctx, rewritten per step; bypass-only)
#define WS_CT    16384     // 16*64*256 ctx_trans (write-once prologue, cached reads)
#define WS_CACHE 278528    // 16*64*256 hist proj rows (same-WG write+read, plain cached)
#define WS_HIST  540672    // 16*64*512 h history rows (write-once per row, bypass write / cached reads)

// out float offsets (hs | cs | ctxs)
#define OUT_HS  0
#define OUT_CS  524288
#define OUT_CTX 1048576

// lds float offsets
#define LDS_WT   0        // 4 quarters x 5136 (2560 K rows * 2 cols interleaved + pad)
#define LDS_ZS   20544    // z-stage [16 b][516]
#define LDS_SCR  28800    // scratch 2048 (gemm reduce / einsum partials / prologue)
#define LDS_GLD  30848    // g lds 16*8
#define LDS_ATT  30976    // aw 256 | av2 256 | abv 256 | araw 64 | asmx 64 | arawZ 64(+pad) | hst 512
#define LDS_FLOATS 32448  // *4 = 129,792 B < 160 KB

typedef float vf4 __attribute__((ext_vector_type(4)));
typedef float vf2 __attribute__((ext_vector_type(2)));

struct CAParams {
  const float* X; const float* ctx; const int* parent; const int* cmask; const float* mask;
  const float* Wx; const float* bx; const float* U; const float* C; const float* P; const float* H;
  const float* acW1; const float* ab1; const float* ahW1; const float* aW2; const float* ab2;
  const float* hhW; const float* hhb; const float* hthW1; const float* hW2; const float* hb2;
  float* out; float* ws;
};

__device__ __forceinline__ float tanh_f(float x) {
  x = fminf(15.f, fmaxf(-15.f, x));
  float e = __expf(2.f * x);
  return (e - 1.f) / (e + 1.f);
}
__device__ __forceinline__ float sigm_f(float x) { return 1.f / (1.f + __expf(-x)); }
__device__ __forceinline__ float wsum(float v) {
  #pragma unroll
  for (int m = 32; m; m >>= 1) v += __shfl_xor(v, m, 64);
  return v;
}
__device__ __forceinline__ float wmax(float v) {
  #pragma unroll
  for (int m = 32; m; m >>= 1) v = fmaxf(v, __shfl_xor(v, m, 64));
  return v;
}
__device__ __forceinline__ float hsum32(float v) {  // reduce within 32-lane half
  #pragma unroll
  for (int m = 16; m; m >>= 1) v += __shfl_xor(v, m, 64);
  return v;
}

// ---- MALL-coherent bypass ops (sc0 sc1), non-atomic so they pipeline ----
__device__ __forceinline__ void bst(float* a, float v) {
  asm volatile("global_store_dword %0, %1, off sc0 sc1" :: "v"(a), "v"(v) : "memory");
}
__device__ __forceinline__ void bst4(float* a, vf4 v) {
  asm volatile("global_store_dwordx4 %0, %1, off sc0 sc1" :: "v"(a), "v"(v) : "memory");
}
__device__ __forceinline__ void bld4x4(vf4* r, const float* p0, const float* p1,
                                       const float* p2, const float* p3) {
  asm volatile(
    "global_load_dwordx4 %0, %4, off sc0 sc1\n"
    "global_load_dwordx4 %1, %5, off sc0 sc1\n"
    "global_load_dwordx4 %2, %6, off sc0 sc1\n"
    "global_load_dwordx4 %3, %7, off sc0 sc1\n"
    "s_waitcnt vmcnt(0)"
    : "=&v"(r[0]), "=&v"(r[1]), "=&v"(r[2]), "=&v"(r[3])
    : "v"(p0), "v"(p1), "v"(p2), "v"(p3) : "memory");
}

__global__ void __launch_bounds__(NT, 1) condatt_kernel(CAParams p) {
  extern __shared__ float lds[];
  float* wt   = lds + LDS_WT;
  float* zs   = lds + LDS_ZS;
  float* scr  = lds + LDS_SCR;
  float* gld  = lds + LDS_GLD;
  float* aw   = lds + LDS_ATT;
  float* av2  = lds + LDS_ATT + 256;
  float* abv  = lds + LDS_ATT + 512;
  float* araw = lds + LDS_ATT + 768;
  float* asmx = lds + LDS_ATT + 832;
  float* arawZ= lds + LDS_ATT + 896;
  float* hst  = lds + LDS_ATT + 960;   // 512

  const int tid = threadIdx.x;
  const int wg  = blockIdx.x;
  float* wsp = p.ws;
  unsigned* flags = (unsigned*)wsp;    // 64B-strided flags, one line per WG
  unsigned nbar = 0;

  // XCD-contiguous column assignment (wg%8 = XCD): co-resident WGs own
  // contiguous column blocks -> weight cache lines fully consumed per XCD.
  const int base = 2 * ((wg & 7) * 32 + (wg >> 3));  // gate col pair {base, base+1}

  // discard stale L1/L2 lines from previous dispatch/poison blit
  __threadfence_system();

  const int kh = tid >> 4, sub = tid & 15, bg = sub >> 2, cp = sub & 3;
  float acc[4][2] = {{0.f,0.f},{0.f,0.f},{0.f,0.f},{0.f,0.f}};
  float hprev = 0.f, cprev = 0.f;  // threads 0..31: per-(b,d) recurrent state

  // Flag-array grid barrier: per-WG flag on its own 64B line (parallel stores,
  // parallel polls, no RMW serialization, no cache maintenance).
  auto gsync = [&]() {
    asm volatile("s_waitcnt vmcnt(0)" ::: "memory");
    __syncthreads();
    ++nbar;
    if (tid == 0)
      __hip_atomic_store(&flags[wg * 16], nbar, __ATOMIC_RELAXED, __HIP_MEMORY_SCOPE_SYSTEM);
    while (__hip_atomic_load(&flags[tid * 16], __ATOMIC_RELAXED, __HIP_MEMORY_SCOPE_SYSTEM) < nbar)
      __builtin_amdgcn_s_sleep(1);
    __syncthreads();
  };

  // ---------------- prologue ----------------
  {
    // ctx_trans = context @ att_ctx_W1 + att_b1 : 4 (b,l)-rows per wg
    for (int j = 0; j < 4; ++j) {
      int rid = wg * 4 + j;  // rid = b*64 + l
      __syncthreads();
      for (int i = tid; i < 512; i += NT) scr[i] = p.ctx[rid * 512 + i];
      __syncthreads();
      float a0 = 0.f, a1 = 0.f, a2 = 0.f, a3 = 0.f;
      for (int c = 0; c < 512; c += 4) {
        a0 += scr[c+0] * p.acW1[(c+0) * 256 + tid];
        a1 += scr[c+1] * p.acW1[(c+1) * 256 + tid];
        a2 += scr[c+2] * p.acW1[(c+2) * 256 + tid];
        a3 += scr[c+3] * p.acW1[(c+3) * 256 + tid];
      }
      bst(wsp + WS_CT + rid * 256 + tid, p.ab1[tid] + ((a0 + a1) + (a2 + a3)));
    }
    __syncthreads();
    // persistent gate-GEMM weights: quarter q, cols (base, base+1); K rows
    // 0..511=Wx, 512..1023=U, 1024..1535=P, 1536..2047=C, 2048..2559=H
    const float* mats[5] = {p.Wx, p.U, p.P, p.C, p.H};
    for (int q = 0; q < 4; ++q) {
      for (int r = tid; r < 2560; r += NT) {
        int m = r >> 9, rr = r & 511;
        vf2 v = *(const vf2*)(mats[m] + rr * 2048 + base + 512 * q);
        *(vf2*)(wt + q * 5136 + r * 2) = v;
      }
    }
    // att WGs: persistent score vectors
    if (wg < 16)            { av2[tid] = p.aW2[tid]; }
    else if (wg < 32)       { av2[tid] = p.hW2[tid]; abv[tid] = p.hhb[tid]; }
    // stage X(0) and do the x-part GEMM before the loop
    #pragma unroll
    for (int j = 0; j < 8; ++j) {
      int i4 = tid + j * NT, b = i4 >> 7, k0 = (i4 << 2) & 511;
      vf4 v = *(const vf4*)(p.X + (b * 64 + 0) * 512 + k0);
      *(vf4*)(zs + b * 516 + k0) = v;
    }
    __syncthreads();
  }

  auto gemm = [&](int comp) {
    const float* wp = wt + cp * 5136 + comp * 1024;
    const float* zb = zs + (bg * 4) * 516;
    #pragma unroll 4
    for (int j = 0; j < 32; ++j) {
      int k = kh + (j << 4);
      vf2 w = *(const vf2*)(wp + k * 2);
      float z0 = zb[k], z1 = zb[516 + k], z2 = zb[1032 + k], z3 = zb[1548 + k];
      acc[0][0] += z0 * w.x; acc[0][1] += z0 * w.y;
      acc[1][0] += z1 * w.x; acc[1][1] += z1 * w.y;
      acc[2][0] += z2 * w.x; acc[2][1] += z2 * w.y;
      acc[3][0] += z3 * w.x; acc[3][1] += z3 * w.y;
    }
  };

  gemm(0);   // x-part for t=0
  gsync();   // publish CT before t=0 attention

  for (int t = 0; t < 64; ++t) {
    // ================= Phase A =================
    // att WGs first (critical path): local proj + attention -> cv / hc
    if (wg < 32) {
      const int b = wg & 15;
      if (tid < 128) {
        vf4 v = {0.f, 0.f, 0.f, 0.f};
        if (t > 0) v = *(const vf4*)(wsp + WS_HIST + (b * 64 + (t - 1)) * 512 + tid * 4);
        *(vf4*)(hst + tid * 4) = v;
      }
      __syncthreads();
      if (wg < 16) {
        // ---- ctx attention ----
        float s = 0.f;
        #pragma unroll 8
        for (int k = 0; k < 512; ++k) s += hst[k] * p.ahW1[k * 256 + tid];
        aw[tid] = s;
        __syncthreads();
        {
          int w = tid >> 6, s32 = tid & 31, hi = (tid >> 5) & 1;
          float b2 = *p.ab2;
          for (int l = w * 2 + hi; l < 64; l += 8) {
            float sc = 0.f;
            #pragma unroll
            for (int q = 0; q < 8; ++q) { int a = s32 + (q << 5); sc += av2[a] * tanh_f(wsp[WS_CT + (b * 64 + l) * 256 + a] + aw[a]); }
            sc = hsum32(sc) + b2;
            if (s32 == 0) araw[l] = (p.cmask[b * 64 + l] > 0) ? -INFINITY : sc;
          }
        }
        __syncthreads();
        if (tid < 64) {
          float r = araw[tid];
          float mx = wmax(r);
          float e = __expf(r - mx);
          float sm = wsum(e);
          asmx[tid] = e / sm;
        }
        __syncthreads();
        {
          int db = tid & 127, half = tid >> 7;
          vf4 a0 = {0.f, 0.f, 0.f, 0.f};
          #pragma unroll 4
          for (int l = half; l < 64; l += 2) {
            float ca = asmx[l];
            vf4 cv = *(const vf4*)(p.ctx + (b * 64 + l) * 512 + db * 4);
            a0.x += ca * cv.x; a0.y += ca * cv.y; a0.z += ca * cv.z; a0.w += ca * cv.w;
          }
          *(vf4*)(scr + tid * 4) = a0;
        }
        __syncthreads();
        if (tid < 128) {
          vf4 u = *(vf4*)(scr + tid * 4), v = *(vf4*)(scr + (tid + 128) * 4);
          u.x += v.x; u.y += v.y; u.z += v.z; u.w += v.w;
          bst4(p.out + OUT_CTX + (b * 64 + t) * 512 + tid * 4, u);
        }
      } else {
        // ---- hist attention ----
        float s1 = 0.f, s2 = 0.f;
        #pragma unroll 8
        for (int k = 0; k < 512; ++k) {
          float hv = hst[k];
          s1 += hv * p.hthW1[k * 256 + tid];
          s2 += hv * p.hhW[k * 256 + tid];
        }
        aw[tid] = s1;
        if (t > 0) wsp[WS_CACHE + (b * 64 + (t - 1)) * 256 + tid] = s2;  // same-WG, plain cached
        __syncthreads();
        {
          int w = tid >> 6, s32 = tid & 31, hi = (tid >> 5) & 1;
          float b2 = *p.hb2;
          for (int l = w * 2 + hi; l < t; l += 8) {
            float sc = 0.f;
            #pragma unroll
            for (int q = 0; q < 8; ++q) { int a = s32 + (q << 5); sc += av2[a] * tanh_f(wsp[WS_CACHE + (b * 64 + l) * 256 + a] + abv[a] + aw[a]); }
            sc = hsum32(sc) + b2;
            if (s32 == 0) araw[l] = sc;
          }
          if (tid < 32) {  // raw value of the (zero) unwritten hist rows
            float sc = 0.f;
            #pragma unroll
            for (int q = 0; q < 8; ++q) { int a = tid + (q << 5); sc += av2[a] * tanh_f(abv[a] + aw[a]); }
            sc = hsum32(sc) + b2;
            if (tid == 0) arawZ[0] = sc;
          }
        }
        __syncthreads();
        if (tid < 64) {
          float r = (tid < t) ? araw[tid] : arawZ[0];
          float mx = wmax(r);                    // max over ALL t' (matches reference)
          float e = (tid < t) ? __expf(r - mx) : 0.f;
          float sm = wsum(e);
          asmx[tid] = e / (sm + 1e-7f);
        }
        __syncthreads();
        {
          int db = tid & 127, half = tid >> 7;
          vf4 a0 = {0.f, 0.f, 0.f, 0.f};
          #pragma unroll 4
          for (int l = half; l < t; l += 2) {
            float hv = asmx[l];
            vf4 hvv = *(const vf4*)(wsp + WS_HIST + (b * 64 + l) * 512 + db * 4);
            a0.x += hv * hvv.x; a0.y += hv * hvv.y; a0.z += hv * hvv.z; a0.w += hv * hvv.w;
          }
          *(vf4*)(scr + tid * 4) = a0;
        }
        __syncthreads();
        if (tid < 128) {
          vf4 u = *(vf4*)(scr + tid * 4), v = *(vf4*)(scr + (tid + 128) * 4);
          u.x += v.x; u.y += v.y; u.z += v.z; u.w += v.w;
          bst4(wsp + WS_HC + b * 512 + tid * 4, u);
        }
      }
    }
    // all WGs: gate-GEMM h and par parts
    __syncthreads();
    if (t == 0) {
      vf4 z = {0.f, 0.f, 0.f, 0.f};
      #pragma unroll
      for (int j = 0; j < 8; ++j) {
        int i4 = tid + j * NT, b = i4 >> 7, k0 = (i4 << 2) & 511;
        *(vf4*)(zs + b * 516 + k0) = z;
      }
    } else {
      #pragma unroll
      for (int j = 0; j < 8; ++j) {
        int i4 = tid + j * NT, b = i4 >> 7, k0 = (i4 << 2) & 511;
        vf4 v = *(const vf4*)(wsp + WS_HIST + (b * 64 + (t - 1)) * 512 + k0);
        *(vf4*)(zs + b * 516 + k0) = v;
      }
    }
    __syncthreads();
    gemm(1);
    __syncthreads();
    {
      #pragma unroll
      for (int j = 0; j < 8; ++j) {
        int i4 = tid + j * NT, b = i4 >> 7, k0 = (i4 << 2) & 511;
        int par = p.parent[b * 64 + t];
        vf4 v = {0.f, 0.f, 0.f, 0.f};
        if (t > 0 && par < t) v = *(const vf4*)(wsp + WS_HIST + (b * 64 + par) * 512 + k0);
        *(vf4*)(zs + b * 516 + k0) = v;
      }
    }
    __syncthreads();
    gemm(2);
    gsync();   // barrier Y: cv / hc published

    // ================= Phase B =================
    {
      #pragma unroll
      for (int j = 0; j < 8; ++j) {  // stage ctx_vec from out (cached; fresh address each step)
        int i4 = tid + j * NT, b = i4 >> 7, k0 = (i4 << 2) & 511;
        vf4 v = *(const vf4*)(p.out + OUT_CTX + (b * 64 + t) * 512 + k0);
        *(vf4*)(zs + b * 516 + k0) = v;
      }
    }
    __syncthreads();
    gemm(3);
    __syncthreads();
    {
      vf4 r[4];
      #pragma unroll
      for (int h2 = 0; h2 < 2; ++h2) {  // stage h_ctx (rewritten buffer -> bypass, batched)
        int i0 = tid + (h2*4+0)*NT, i1 = tid + (h2*4+1)*NT, i2 = tid + (h2*4+2)*NT, i3 = tid + (h2*4+3)*NT;
        bld4x4(r,
               wsp + WS_HC + (i0 >> 7) * 512 + ((i0 << 2) & 511),
               wsp + WS_HC + (i1 >> 7) * 512 + ((i1 << 2) & 511),
               wsp + WS_HC + (i2 >> 7) * 512 + ((i2 << 2) & 511),
               wsp + WS_HC + (i3 >> 7) * 512 + ((i3 << 2) & 511));
        *(vf4*)(zs + (i0 >> 7) * 516 + ((i0 << 2) & 511)) = r[0];
        *(vf4*)(zs + (i1 >> 7) * 516 + ((i1 << 2) & 511)) = r[1];
        *(vf4*)(zs + (i2 >> 7) * 516 + ((i2 << 2) & 511)) = r[2];
        *(vf4*)(zs + (i3 >> 7) * 516 + ((i3 << 2) & 511)) = r[3];
      }
    }
    __syncthreads();
    gemm(4);
    {
      float* s8 = scr + (kh * 16 + sub) * 8;
      #pragma unroll
      for (int i = 0; i < 4; ++i) { s8[i*2] = acc[i][0]; s8[i*2+1] = acc[i][1]; acc[i][0] = 0.f; acc[i][1] = 0.f; }
    }
    __syncthreads();
    if (t < 63) {
      #pragma unroll
      for (int j = 0; j < 8; ++j) {  // pre-stage X(t+1)
        int i4 = tid + j * NT, b = i4 >> 7, k0 = (i4 << 2) & 511;
        vf4 v = *(const vf4*)(p.X + (b * 64 + (t + 1)) * 512 + k0);
        *(vf4*)(zs + b * 516 + k0) = v;
      }
    }
    if (tid < 128) {
      int b = tid >> 3, c = tid & 7;  // c = quarter*2 + coloff
      int n = base + (c & 1) + 512 * (c >> 1);
      float g = p.bx[n];
      int sidx = (b >> 2) * 4 + (c >> 1);
      int aidx = (b & 3) * 2 + (c & 1);
      #pragma unroll
      for (int k2 = 0; k2 < 16; ++k2) g += scr[(k2 * 16 + sidx) * 8 + aidx];
      gld[b * 8 + c] = g;
    }
    __syncthreads();
    if (tid < 32) {
      int b = tid >> 1, dj = tid & 1;
      int d = base + dj;
      float gi = gld[b*8 + 0 + dj];
      float gf = gld[b*8 + 2 + dj];
      float gg = gld[b*8 + 4 + dj];
      float go = gld[b*8 + 6 + dj];
      float i_ = sigm_f(gi), f_ = sigm_f(gf), o_ = sigm_f(go);
      float cn = f_ * cprev + i_ * tanh_f(gg);
      float hn = o_ * tanh_f(cn);
      float m_ = p.mask[b * 64 + t];
      hn = (1.f - m_) * hprev + m_ * hn;
      cn = (1.f - m_) * cprev + m_ * cn;
      hprev = hn; cprev = cn;
      bst(wsp + WS_HIST + (b * 64 + t) * 512 + d, hn);
      p.out[OUT_HS + (b * 64 + t) * 512 + d] = hn;
      p.out[OUT_CS + (b * 64 + t) * 512 + d] = cn;
    }
    if (t < 63) {
      gemm(0);   // x-part for t+1 (zs holds X(t+1))
      gsync();   // barrier X: h(t) published
    }
  }
}

extern "C" void kernel_launch(void* const* d_in, const int* in_sizes, int n_in,
                              void* d_out, int out_size, void* d_ws, size_t ws_size,
                              hipStream_t stream) {
  CAParams p;
  p.X      = (const float*)d_in[0];
  p.ctx    = (const float*)d_in[1];
  p.parent = (const int*)  d_in[2];
  p.cmask  = (const int*)  d_in[3];
  p.mask   = (const float*)d_in[4];
  p.Wx = (const float*)d_in[5];  p.bx = (const float*)d_in[6];
  p.U  = (const float*)d_in[7];  p.C  = (const float*)d_in[8];
  p.P  = (const float*)d_in[9];  p.H  = (const float*)d_in[10];
  p.acW1 = (const float*)d_in[11]; p.ab1 = (const float*)d_in[12];
  p.ahW1 = (const float*)d_in[13]; p.aW2 = (const float*)d_in[14]; p.ab2 = (const float*)d_in[15];
  p.hhW  = (const float*)d_in[16]; p.hhb = (const float*)d_in[17];
  p.hthW1= (const float*)d_in[18]; p.hW2 = (const float*)d_in[19]; p.hb2 = (const float*)d_in[20];
  p.out = (float*)d_out;
  p.ws  = (float*)d_ws;

  // reset barrier flags (nbar restarts at 1 each launch)
  (void)hipMemsetAsync(d_ws, 0, 16384, stream);

  static_assert(LDS_FLOATS * 4 <= 160 * 1024, "LDS budget");
  (void)hipFuncSetAttribute((const void*)condatt_kernel,
                      hipFuncAttributeMaxDynamicSharedMemorySize, LDS_FLOATS * 4);
  hipLaunchKernelGGL(condatt_kernel, dim3(NWG), dim3(NT), LDS_FLOATS * 4, stream, p);
}